// Round 10
// baseline (139.768 us; speedup 1.0000x reference)
//
#include <hip/hip_runtime.h>
#include <hip/hip_bf16.h>

// MoE fused block, MI355X gfx950.
// Shapes: B=2, C=256, T*H*W=16384, E=4, K=2. All inputs fp32, output fp32.
//
// R14 -> R15: LDS-port test. Cycle model: A-frag ds_read_b128 ~12cy of
// CU-wide LDS port; R14 = 8192 reads/CU ~= 98K cy of a 125K-cy kernel ->
// the port is the wall (explains all prior nulls). This round halves A-read
// redundancy by re-tiling waves (nv8 x Mt4) -> (nv4 x mh2): each wave owns
// 64 chans x 32 pos. A-reads/wave/expert/GEMM 32 -> 16 (LDS 98K -> 49K cy);
// B-loads double (TA 33K -> 66K cy, different port). This is R11's tiling
// WITHOUT its confounds: dense GEMM1 (no gather/round-robin/mt-dispatch),
// setprio kept, ring-2 kept, MT=64, 2 WGs/CU. Registers: hacc[2][4] +
// oacc[2][4] = 64 acc; bw[2][4] + a[2] = 40 arch -- same 64+64 envelope.
// Pre-registered read: regression => B-path binds, pivot to W-in-LDS.

#define C_DIM 256
#define S_DIM 16384          // T*H*W
#define E_DIM 4
#define MT 64                // positions per workgroup
#define XST 264              // Xs/Hs row stride in shorts (16B-aligned rows)
#define WFRAG_ELEMS 262144   // elements per prepacked weight tensor (4*16*8*64*8)

typedef __attribute__((ext_vector_type(8))) short bf16x8;
typedef __attribute__((ext_vector_type(4))) float f32x4;

__device__ __forceinline__ short bfq(float f) {
  __hip_bfloat16 h = __float2bfloat16(f);
  return *(short*)&h;
}

// Prepack: dst[(half,e,nt,kc,lane,j)] = src[(e*256 + nt*16 + (lane&15))*256
//                                           + kc*32 + (lane>>4)*8 + j]
// B-operand fragment layout for mfma_f32_16x16x32_bf16: n=lane&15, k=(lane>>4)*8+j.
// 32 consecutive threads read one contiguous 1KB source row (fully coalesced);
// the 16B fragment stores scatter (fire-and-forget).
__global__ __launch_bounds__(256) void prepack_kernel(
    const float* __restrict__ w1, const float* __restrict__ w2,
    __hip_bfloat16* __restrict__ dst)
{
  int o8   = blockIdx.x * 256 + threadIdx.x;  // 0 .. 65535 (8-elem chunks)
  int half = o8 >> 15;                        // 0: w1, 1: w2
  int idx  = o8 & 32767;
  int j    = idx & 31;                        // 8-float chunk within source row
  int rowid= idx >> 5;                        // e*256 + nt*16 + row, 0..1023
  int e    = rowid >> 8;
  int nt   = (rowid >> 4) & 15;
  int row  = rowid & 15;
  int kc   = j >> 2;
  int col8 = j & 3;
  int lane = (col8 << 4) | row;
  const float* src = half ? w2 : w1;
  const float* s = src + rowid * 256 + j * 8;
  const float4 v0 = *(const float4*)s;
  const float4 v1 = *(const float4*)(s + 4);
  bf16x8 outv = {bfq(v0.x), bfq(v0.y), bfq(v0.z), bfq(v0.w),
                 bfq(v1.x), bfq(v1.y), bfq(v1.z), bfq(v1.w)};
  int chunk = ((e*16 + nt)*8 + kc)*64 + lane;
  *(bf16x8*)((short*)dst + half*WFRAG_ELEMS + chunk*8) = outv;
}

// Dense GEMM1, wave tile = 32 pos (mh half) x 64 chan (nv quarter).
// Barrier (protecting Hs readers of the previous expert's GEMM2) sits
// BETWEEN the MFMA loop and the H-scatter. Ring-2 weight prefetch; setprio
// across the MFMA cluster. Weighted scatter covers all rows (wg=0 -> zeros).
__device__ __forceinline__ void gemm1_dense(
    const short* XsS, short* HsS, const short* w1e, const float* b1e,
    const float* WgtE, int nv, int mh, int r, int q, bool dosync)
{
  f32x4 hacc[2][4];
#pragma unroll
  for (int i = 0; i < 2; ++i)
#pragma unroll
    for (int t = 0; t < 4; ++t) hacc[i][t] = (f32x4){0.f, 0.f, 0.f, 0.f};

  bf16x8 bw[2][4];
#pragma unroll
  for (int t = 0; t < 4; ++t) bw[0][t] = *(const bf16x8*)(w1e + (t*8 + 0)*512);
  __builtin_amdgcn_s_setprio(1);
#pragma unroll
  for (int kc = 0; kc < 8; ++kc) {
    if (kc < 7) {
#pragma unroll
      for (int t = 0; t < 4; ++t)
        bw[(kc+1)&1][t] = *(const bf16x8*)(w1e + (t*8 + kc + 1)*512);
    }
    bf16x8 a[2];
#pragma unroll
    for (int Mt = 0; Mt < 2; ++Mt)
      a[Mt] = *(const bf16x8*)(XsS + (mh*32 + Mt*16 + r)*XST + kc*32 + q*8);
#pragma unroll
    for (int Mt = 0; Mt < 2; ++Mt)
#pragma unroll
      for (int t = 0; t < 4; ++t)
        hacc[Mt][t] = __builtin_amdgcn_mfma_f32_16x16x32_bf16(a[Mt], bw[kc&1][t], hacc[Mt][t], 0, 0, 0);
  }
  __builtin_amdgcn_s_setprio(0);

  if (dosync) __syncthreads();   // prev expert's GEMM2 done reading Hs

  // epilogue: +b1, fast SiLU, scale by gate weight (0 -> exact zeros),
  // scatter to Hs. p = mh*32 + Mt*16 + q*4 + reg; n = nv*64 + t*16 + r.
#pragma unroll
  for (int Mt = 0; Mt < 2; ++Mt) {
    const f32x4 wg = *(const f32x4*)(WgtE + mh*32 + Mt*16 + q*4);
#pragma unroll
    for (int t = 0; t < 4; ++t) {
      const int n = nv*64 + t*16 + r;
      const float bias = b1e[n];
#pragma unroll
      for (int reg = 0; reg < 4; ++reg) {
        const int p = mh*32 + Mt*16 + q*4 + reg;
        const float z = hacc[Mt][t][reg] + bias;
        const float s = __builtin_amdgcn_rcpf(1.0f + __expf(-z));
        HsS[p*XST + n] = bfq(z * s * wg[reg]);
      }
    }
  }
}

__global__ __launch_bounds__(512, 4) void moe_fused_kernel(
    const float* __restrict__ x,
    const float* __restrict__ gate_w,
    const float* __restrict__ gate_b,
    const float* __restrict__ b1,
    const float* __restrict__ b2,
    const __hip_bfloat16* __restrict__ wp,   // [W1P | W2P] prepacked bf16
    float* __restrict__ out)
{
  // pool (67584 B): Xs (33792) + Hs (33792).
  // Gate fp64 partials (16KB) alias the Hs region before its first use.
  __shared__ __align__(16) char pool[2 * MT * XST * 2];
  __shared__ __align__(16) float Wgt[4][MT];   // gate weights, e-major

  short* XsS = (short*)pool;
  short* HsS = (short*)(pool + MT * XST * 2);

  const int tid  = threadIdx.x;
  const int lane = tid & 63;
  const int wv   = tid >> 6;     // wave 0..7
  const int nv   = wv & 3;       // chan-group: [nv*64, nv*64+64)
  const int mh   = wv >> 2;      // pos-half:   [mh*32, mh*32+32)
  const int r    = lane & 15;
  const int q    = lane >> 4;

  const int g  = blockIdx.x;
  const int b  = g >> 8;                 // 256 workgroups per batch
  const int s0 = (g & 255) * MT;
  const float* xb = x + (size_t)b * C_DIM * S_DIM + s0;

  const short* W1P = (const short*)wp;
  const short* W2P = (const short*)wp + WFRAG_ELEMS;

  // ---- FUSED stage X + gate partials (staging wave map unchanged: wave wv
  //      owns channels [wv*32, wv*32+32), lane = position). ----
  {
    const int p  = lane;
    const int c0 = wv * 32;
    float xv[32];
#pragma unroll
    for (int j = 0; j < 32; ++j)
      xv[j] = xb[(size_t)(c0 + j) * S_DIM + p];

    double acc[4] = {0.0, 0.0, 0.0, 0.0};
#pragma unroll
    for (int j = 0; j < 32; ++j) {
      const double xd = (double)xv[j];
      acc[0] += xd * (double)gate_w[0*256 + c0 + j];
      acc[1] += xd * (double)gate_w[1*256 + c0 + j];
      acc[2] += xd * (double)gate_w[2*256 + c0 + j];
      acc[3] += xd * (double)gate_w[3*256 + c0 + j];
    }

#pragma unroll
    for (int k = 0; k < 4; ++k) {
      bf16x8 blk = {bfq(xv[k*8+0]), bfq(xv[k*8+1]), bfq(xv[k*8+2]), bfq(xv[k*8+3]),
                    bfq(xv[k*8+4]), bfq(xv[k*8+5]), bfq(xv[k*8+6]), bfq(xv[k*8+7])};
      *(bf16x8*)(XsS + p*XST + c0 + k*8) = blk;
    }

    double* GateD = (double*)HsS;   // 64pos x 4e x 8grp fp64 = 16KB (alias)
#pragma unroll
    for (int e = 0; e < 4; ++e)
      GateD[(e*8 + wv)*64 + p] = acc[e];
  }
  __syncthreads();   // Xs staged AND gate partials written

  // ---- logits (fp64 reduce, fixed order) + top-2 + softmax, fused via shfl ----
  if (tid < 256) {
    const int p = tid >> 2;
    const int e = tid & 3;
    const double* GateD = (const double*)HsS;
    double s = (double)gate_b[e];
#pragma unroll
    for (int g2 = 0; g2 < 8; ++g2) s += GateD[(e*8 + g2)*64 + p];
    const float la = (float)s;              // l[e]
    const float lb = __shfl_xor(la, 1, 64); // l[e^1]
    const float lc = __shfl_xor(la, 2, 64); // l[e^2]
    const float ld = __shfl_xor(lb, 2, 64); // l[e^3]
    if (e == 0) {
      const float l0 = la, l1 = lb, l2 = lc, l3 = ld;
      int i1 = 0; float v1 = l0;
      if (l1 > v1) { v1 = l1; i1 = 1; }
      if (l2 > v1) { v1 = l2; i1 = 2; }
      if (l3 > v1) { v1 = l3; i1 = 3; }
      float v2 = -3.0e38f; int i2 = 0;
      if (i1 != 0 && l0 > v2) { v2 = l0; i2 = 0; }
      if (i1 != 1 && l1 > v2) { v2 = l1; i2 = 1; }
      if (i1 != 2 && l2 > v2) { v2 = l2; i2 = 2; }
      if (i1 != 3 && l3 > v2) { v2 = l3; i2 = 3; }
      const float wA = 1.0f / (1.0f + __expf(v2 - v1));
      const float wB = 1.0f - wA;
      Wgt[0][p] = (i1 == 0) ? wA : ((i2 == 0) ? wB : 0.0f);
      Wgt[1][p] = (i1 == 1) ? wA : ((i2 == 1) ? wB : 0.0f);
      Wgt[2][p] = (i1 == 2) ? wA : ((i2 == 2) ? wB : 0.0f);
      Wgt[3][p] = (i1 == 3) ? wA : ((i2 == 3) ? wB : 0.0f);
    }
  }
  __syncthreads();   // Wgt final (also: GateD fully consumed before H-scatter)

  f32x4 oacc[2][4];   // [Mt][t]: persistent out accumulator, K=1024 concat
#pragma unroll
  for (int i = 0; i < 2; ++i)
#pragma unroll
    for (int t = 0; t < 4; ++t) oacc[i][t] = (f32x4){0.f, 0.f, 0.f, 0.f};

  for (int e = 0; e < E_DIM; ++e) {
    const short* w1e = W1P + ((e*16 + nv*4)*8)*512 + lane*8;
    const bool dosync = (e > 0);   // wait for prev GEMM2's Hs readers

    gemm1_dense(XsS, HsS, w1e, b1 + e*256, &Wgt[e][0], nv, mh, r, q, dosync);

    // GEMM2 prologue: first kc B-fragments, issued before the barrier
    const short* w2e = W2P + ((e*16 + nv*4)*8)*512 + lane*8;
    bf16x8 cw[2][4];
#pragma unroll
    for (int t = 0; t < 4; ++t) cw[0][t] = *(const bf16x8*)(w2e + (t*8 + 0)*512);

    __syncthreads();   // Hs complete (weighted scatter covers all 64 rows)

    // ---- GEMM2: oacc += H_e(64x256) @ W2_e^T slice, ring-2 prefetch.
    //      This wave: pos rows [mh*32, mh*32+32) x chans [nv*64, nv*64+64). ----
    {
      __builtin_amdgcn_s_setprio(1);
#pragma unroll
      for (int kc = 0; kc < 8; ++kc) {
        if (kc < 7) {
#pragma unroll
          for (int t = 0; t < 4; ++t)
            cw[(kc+1)&1][t] = *(const bf16x8*)(w2e + (t*8 + kc + 1)*512);
        }
        bf16x8 a[2];
#pragma unroll
        for (int Mt = 0; Mt < 2; ++Mt)
          a[Mt] = *(const bf16x8*)(HsS + (mh*32 + Mt*16 + r)*XST + kc*32 + q*8);
#pragma unroll
        for (int Mt = 0; Mt < 2; ++Mt)
#pragma unroll
          for (int t = 0; t < 4; ++t)
            oacc[Mt][t] = __builtin_amdgcn_mfma_f32_16x16x32_bf16(a[Mt], cw[kc&1][t], oacc[Mt][t], 0, 0, 0);
      }
      __builtin_amdgcn_s_setprio(0);
    }
    // no barrier here: next expert's GEMM1 compute doesn't touch Hs; the
    // barrier protecting Hs sits inside gemm1_dense, before its scatter.
  }

  // ---- O epilogue: direct stores. Lane holds 4 CONSECUTIVE positions per
  //      fragment (D row = q*4+reg): float4 res/store per (Mt,t). Reads Wgt
  //      (stable LDS, e-major) + regs: no barrier. ----
  {
    float b2v[4][4];   // [t][e] for c = nv*64 + t*16 + r
#pragma unroll
    for (int t = 0; t < 4; ++t) {
      const int c = nv*64 + t*16 + r;
#pragma unroll
      for (int e = 0; e < 4; ++e) b2v[t][e] = b2[e*256 + c];
    }
    float* ob = out + (size_t)b * C_DIM * S_DIM + s0;
#pragma unroll
    for (int Mt = 0; Mt < 2; ++Mt) {
      const int pb = mh*32 + Mt*16 + q*4;
      f32x4 wge[4];
#pragma unroll
      for (int e = 0; e < 4; ++e)
        wge[e] = *(const f32x4*)(&Wgt[e][pb]);
#pragma unroll
      for (int t = 0; t < 4; ++t) {
        const int c = nv*64 + t*16 + r;
        f32x4 v = oacc[Mt][t];
#pragma unroll
        for (int reg = 0; reg < 4; ++reg)
          v[reg] += wge[0][reg]*b2v[t][0] + wge[1][reg]*b2v[t][1]
                  + wge[2][reg]*b2v[t][2] + wge[3][reg]*b2v[t][3];
        const float4 xr = *(const float4*)(xb + (size_t)c*S_DIM + pb);
        float4 res;
        res.x = v[0] + xr.x; res.y = v[1] + xr.y;
        res.z = v[2] + xr.z; res.w = v[3] + xr.w;
        *(float4*)(ob + (size_t)c*S_DIM + pb) = res;
      }
    }
  }
}

extern "C" void kernel_launch(void* const* d_in, const int* in_sizes, int n_in,
                              void* d_out, int out_size, void* d_ws, size_t ws_size,
                              hipStream_t stream)
{
  (void)in_sizes; (void)n_in; (void)out_size; (void)ws_size;
  const float* x      = (const float*)d_in[0];
  const float* gate_w = (const float*)d_in[1];
  const float* gate_b = (const float*)d_in[2];
  const float* w1     = (const float*)d_in[3];
  const float* b1     = (const float*)d_in[4];
  const float* w2     = (const float*)d_in[5];
  const float* b2     = (const float*)d_in[6];
  float* out = (float*)d_out;
  __hip_bfloat16* wpack = (__hip_bfloat16*)d_ws;   // needs 1 MiB of scratch

  prepack_kernel<<<256, 256, 0, stream>>>(w1, w2, wpack);
  moe_fused_kernel<<<512, 512, 0, stream>>>(x, gate_w, gate_b, b1, b2, wpack, out);
}